// Round 1
// baseline (205.769 us; speedup 1.0000x reference)
//
#include <hip/hip_runtime.h>
#include <stdint.h>

typedef __attribute__((ext_vector_type(4))) float f32x4;
typedef __attribute__((ext_vector_type(8))) short s16x8;

__device__ __forceinline__ unsigned short tobf(float x) {
  uint32_t u = __builtin_bit_cast(uint32_t, x);
  u += 0x7fffu + ((u >> 16) & 1u);   // RNE
  return (unsigned short)(u >> 16);
}

// ---------------- fp32 -> bf16 convert ----------------
__global__ __launch_bounds__(256) void cvt_kernel(const float* __restrict__ in,
                                                  unsigned short* __restrict__ out, int n4) {
  int i = blockIdx.x * 256 + threadIdx.x;
  if (i >= n4) return;
  float4 v = reinterpret_cast<const float4*>(in)[i];
  ushort4 o;
  o.x = tobf(v.x); o.y = tobf(v.y); o.z = tobf(v.z); o.w = tobf(v.w);
  reinterpret_cast<ushort4*>(out)[i] = o;
}

// ---------------- fused QKV projection: C = xb @ W^T ----------------
// grid (32, 18): y in [0,6)->Q, [6,12)->K, [12,18)->V ; 128x128 tile, 4 waves.
__global__ __launch_bounds__(256) void qkv_gemm(
    const unsigned short* __restrict__ xb,
    const unsigned short* __restrict__ wq,
    const unsigned short* __restrict__ wk,
    const unsigned short* __restrict__ wv,
    unsigned short* __restrict__ q_ws,
    unsigned short* __restrict__ k_ws,
    unsigned short* __restrict__ vt_ws) {
  __shared__ unsigned short As[128][40];  // +8 pad: row stride 80B -> 2-way max
  __shared__ unsigned short Bs[128][40];
  const int t = threadIdx.x;
  const int l = t & 63, w = t >> 6;
  const int wm = w >> 1, wn = w & 1;
  const int lr = l & 15, lg = l >> 4;
  const int tileM = blockIdx.x * 128;
  const int nt = blockIdx.y;
  const int wsel = nt / 6;
  const unsigned short* W = (wsel == 0) ? wq : ((wsel == 1) ? wk : wv);
  const int tileN = (nt % 6) * 128;

  f32x4 acc[4][4];
  const f32x4 z4 = {0.f, 0.f, 0.f, 0.f};
#pragma unroll
  for (int i = 0; i < 4; ++i)
#pragma unroll
    for (int j = 0; j < 4; ++j) acc[i][j] = z4;

  for (int k0 = 0; k0 < 768; k0 += 32) {
    __syncthreads();
#pragma unroll
    for (int i = 0; i < 2; ++i) {
      int L = i * 256 + t;
      int row = L >> 2, cb = (L & 3) * 8;
      *(uint4*)&As[row][cb] = *(const uint4*)&xb[(tileM + row) * 768 + k0 + cb];
      *(uint4*)&Bs[row][cb] = *(const uint4*)&W[(tileN + row) * 768 + k0 + cb];
    }
    __syncthreads();
    s16x8 a[4], b[4];
#pragma unroll
    for (int mi = 0; mi < 4; ++mi) a[mi] = *(const s16x8*)&As[wm * 64 + mi * 16 + lr][lg * 8];
#pragma unroll
    for (int ni = 0; ni < 4; ++ni) b[ni] = *(const s16x8*)&Bs[wn * 64 + ni * 16 + lr][lg * 8];
#pragma unroll
    for (int mi = 0; mi < 4; ++mi)
#pragma unroll
      for (int ni = 0; ni < 4; ++ni)
        acc[mi][ni] = __builtin_amdgcn_mfma_f32_16x16x32_bf16(a[mi], b[ni], acc[mi][ni], 0, 0, 0);
  }

#pragma unroll
  for (int mi = 0; mi < 4; ++mi)
#pragma unroll
    for (int ni = 0; ni < 4; ++ni)
#pragma unroll
      for (int r = 0; r < 4; ++r) {
        int m = tileM + wm * 64 + mi * 16 + lg * 4 + r;
        int n = tileN + wn * 64 + ni * 16 + lr;
        int bb = m >> 11, sq = m & 2047;
        int h = n >> 6, dh = n & 63;
        float v = acc[mi][ni][r];
        if (wsel == 0)       // Q, pre-scaled by 1/sqrt(Dh)
          q_ws[((bb * 12 + h) * 2048 + sq) * 64 + dh] = tobf(v * 0.125f);
        else if (wsel == 1)  // K
          k_ws[((bb * 12 + h) * 2048 + sq) * 64 + dh] = tobf(v);
        else                 // V stored transposed: [b,h,64,s]
          vt_ws[((bb * 12 + h) * 64 + dh) * 2048 + sq] = tobf(v);
      }
}

// ---------------- flash attention (causal) ----------------
// grid (16, 24): x -> q-tile (reversed for load balance), y -> b*12+h.
// Block: 128 q-rows, 4 waves x 32 rows; k-tiles of 64.
__global__ __launch_bounds__(256) void attn_kernel(
    const unsigned short* __restrict__ q_ws,
    const unsigned short* __restrict__ k_ws,
    const unsigned short* __restrict__ vt_ws,
    unsigned short* __restrict__ ctx) {
  __shared__ unsigned short Ks[64][72];      // [k][d]
  __shared__ unsigned short Vs[64][72];      // V^T tile: [dh][k]
  __shared__ unsigned short Ps[4][32][72];   // wave-private P tiles [q][k]

  const int t = threadIdx.x;
  const int l = t & 63, w = t >> 6;
  const int lr = l & 15, lg = l >> 4;
  const int qt = 15 - (int)blockIdx.x;
  const int bh = blockIdx.y;
  const int q0 = qt * 128 + w * 32;

  s16x8 qa[2][2];  // Q hoisted to registers (already scaled by 0.125)
#pragma unroll
  for (int mi = 0; mi < 2; ++mi)
#pragma unroll
    for (int kk = 0; kk < 2; ++kk)
      qa[mi][kk] = *(const s16x8*)&q_ws[(bh * 2048 + q0 + mi * 16 + lr) * 64 + kk * 32 + lg * 8];

  f32x4 o[2][4];
  const f32x4 z4 = {0.f, 0.f, 0.f, 0.f};
  float mrow[2][4], lrow[2][4];
#pragma unroll
  for (int mi = 0; mi < 2; ++mi)
#pragma unroll
    for (int r = 0; r < 4; ++r) {
      mrow[mi][r] = -1e30f;
      lrow[mi][r] = 0.f;
#pragma unroll
      for (int di = 0; di < 4; ++di) o[mi][di] = z4;
    }

  const int ktmax = 2 * qt + 1;
  for (int kt = 0; kt <= ktmax; ++kt) {
    __syncthreads();
#pragma unroll
    for (int i = 0; i < 2; ++i) {
      int L = i * 256 + t;
      int row = L >> 3, cb = (L & 7) * 8;
      *(uint4*)&Ks[row][cb] = *(const uint4*)&k_ws[(bh * 2048 + kt * 64 + row) * 64 + cb];
      *(uint4*)&Vs[row][cb] = *(const uint4*)&vt_ws[(bh * 64 + row) * 2048 + kt * 64 + cb];
    }
    __syncthreads();

    // S = Q K^T  (32 x 64 per wave)
    f32x4 s[2][4];
#pragma unroll
    for (int mi = 0; mi < 2; ++mi)
#pragma unroll
      for (int ni = 0; ni < 4; ++ni) s[mi][ni] = z4;
#pragma unroll
    for (int kk = 0; kk < 2; ++kk) {
      s16x8 kb[4];
#pragma unroll
      for (int ni = 0; ni < 4; ++ni) kb[ni] = *(const s16x8*)&Ks[ni * 16 + lr][kk * 32 + lg * 8];
#pragma unroll
      for (int mi = 0; mi < 2; ++mi)
#pragma unroll
        for (int ni = 0; ni < 4; ++ni)
          s[mi][ni] = __builtin_amdgcn_mfma_f32_16x16x32_bf16(qa[mi][kk], kb[ni], s[mi][ni], 0, 0, 0);
    }

    if (kt >= 2 * qt) {  // only diagonal-straddling tiles need the mask
#pragma unroll
      for (int mi = 0; mi < 2; ++mi)
#pragma unroll
        for (int ni = 0; ni < 4; ++ni)
#pragma unroll
          for (int r = 0; r < 4; ++r) {
            int kg = kt * 64 + ni * 16 + lr;
            int qg = q0 + mi * 16 + lg * 4 + r;
            if (kg > qg) s[mi][ni][r] = -1e30f;
          }
    }

    // online softmax (per-row stats; rows live in 16-lane groups)
    float pm[2][4], sc[2][4], rs[2][4];
#pragma unroll
    for (int mi = 0; mi < 2; ++mi)
#pragma unroll
      for (int r = 0; r < 4; ++r) {
        float v = fmaxf(fmaxf(s[mi][0][r], s[mi][1][r]), fmaxf(s[mi][2][r], s[mi][3][r]));
#pragma unroll
        for (int off = 1; off <= 8; off <<= 1) v = fmaxf(v, __shfl_xor(v, off, 64));
        pm[mi][r] = v;
      }
#pragma unroll
    for (int mi = 0; mi < 2; ++mi)
#pragma unroll
      for (int r = 0; r < 4; ++r) {
        float mn = fmaxf(mrow[mi][r], pm[mi][r]);
        sc[mi][r] = __expf(mrow[mi][r] - mn);
        mrow[mi][r] = mn;
        rs[mi][r] = 0.f;
      }
#pragma unroll
    for (int mi = 0; mi < 2; ++mi)
#pragma unroll
      for (int ni = 0; ni < 4; ++ni)
#pragma unroll
        for (int r = 0; r < 4; ++r) {
          float p = __expf(s[mi][ni][r] - mrow[mi][r]);
          s[mi][ni][r] = p;
          rs[mi][r] += p;
        }
#pragma unroll
    for (int mi = 0; mi < 2; ++mi)
#pragma unroll
      for (int r = 0; r < 4; ++r) {
        float v = rs[mi][r];
#pragma unroll
        for (int off = 1; off <= 8; off <<= 1) v += __shfl_xor(v, off, 64);
        lrow[mi][r] = lrow[mi][r] * sc[mi][r] + v;
      }
#pragma unroll
    for (int mi = 0; mi < 2; ++mi)
#pragma unroll
      for (int di = 0; di < 4; ++di)
#pragma unroll
        for (int r = 0; r < 4; ++r) o[mi][di][r] *= sc[mi][r];

    // P -> bf16 -> wave-private LDS (re-fragment for PV A-operand)
#pragma unroll
    for (int mi = 0; mi < 2; ++mi)
#pragma unroll
      for (int ni = 0; ni < 4; ++ni)
#pragma unroll
        for (int r = 0; r < 4; ++r)
          Ps[w][mi * 16 + lg * 4 + r][ni * 16 + lr] = tobf(s[mi][ni][r]);

    // O += P @ V
#pragma unroll
    for (int kk = 0; kk < 2; ++kk) {
      s16x8 pa[2], vb[4];
#pragma unroll
      for (int mi = 0; mi < 2; ++mi) pa[mi] = *(const s16x8*)&Ps[w][mi * 16 + lr][kk * 32 + lg * 8];
#pragma unroll
      for (int di = 0; di < 4; ++di) vb[di] = *(const s16x8*)&Vs[di * 16 + lr][kk * 32 + lg * 8];
#pragma unroll
      for (int mi = 0; mi < 2; ++mi)
#pragma unroll
        for (int di = 0; di < 4; ++di)
          o[mi][di] = __builtin_amdgcn_mfma_f32_16x16x32_bf16(pa[mi], vb[di], o[mi][di], 0, 0, 0);
    }
  }

  const int bb = bh / 12, h = bh % 12;
#pragma unroll
  for (int mi = 0; mi < 2; ++mi)
#pragma unroll
    for (int r = 0; r < 4; ++r) {
      float rl = 1.0f / lrow[mi][r];
      int qg = q0 + mi * 16 + lg * 4 + r;
#pragma unroll
      for (int di = 0; di < 4; ++di)
        ctx[(bb * 2048 + qg) * 768 + h * 64 + di * 16 + lr] = tobf(o[mi][di][r] * rl);
    }
}

// ---------------- output projection: out = ctx @ Wo^T + bo (fp32 out) ----------------
__global__ __launch_bounds__(256) void out_gemm(
    const unsigned short* __restrict__ ctxb,
    const unsigned short* __restrict__ wo,
    const float* __restrict__ bo,
    float* __restrict__ out) {
  __shared__ unsigned short As[128][40];
  __shared__ unsigned short Bs[128][40];
  const int t = threadIdx.x;
  const int l = t & 63, w = t >> 6;
  const int wm = w >> 1, wn = w & 1;
  const int lr = l & 15, lg = l >> 4;
  const int tileM = blockIdx.x * 128;
  const int tileN = blockIdx.y * 128;

  f32x4 acc[4][4];
  const f32x4 z4 = {0.f, 0.f, 0.f, 0.f};
#pragma unroll
  for (int i = 0; i < 4; ++i)
#pragma unroll
    for (int j = 0; j < 4; ++j) acc[i][j] = z4;

  for (int k0 = 0; k0 < 768; k0 += 32) {
    __syncthreads();
#pragma unroll
    for (int i = 0; i < 2; ++i) {
      int L = i * 256 + t;
      int row = L >> 2, cb = (L & 3) * 8;
      *(uint4*)&As[row][cb] = *(const uint4*)&ctxb[(tileM + row) * 768 + k0 + cb];
      *(uint4*)&Bs[row][cb] = *(const uint4*)&wo[(tileN + row) * 768 + k0 + cb];
    }
    __syncthreads();
    s16x8 a[4], b[4];
#pragma unroll
    for (int mi = 0; mi < 4; ++mi) a[mi] = *(const s16x8*)&As[wm * 64 + mi * 16 + lr][lg * 8];
#pragma unroll
    for (int ni = 0; ni < 4; ++ni) b[ni] = *(const s16x8*)&Bs[wn * 64 + ni * 16 + lr][lg * 8];
#pragma unroll
    for (int mi = 0; mi < 4; ++mi)
#pragma unroll
      for (int ni = 0; ni < 4; ++ni)
        acc[mi][ni] = __builtin_amdgcn_mfma_f32_16x16x32_bf16(a[mi], b[ni], acc[mi][ni], 0, 0, 0);
  }

#pragma unroll
  for (int mi = 0; mi < 4; ++mi)
#pragma unroll
    for (int ni = 0; ni < 4; ++ni)
#pragma unroll
      for (int r = 0; r < 4; ++r) {
        int m = tileM + wm * 64 + mi * 16 + lg * 4 + r;
        int n = tileN + wn * 64 + ni * 16 + lr;
        out[m * 768 + n] = acc[mi][ni][r] + bo[n];
      }
}

// ---------------- launch ----------------
extern "C" void kernel_launch(void* const* d_in, const int* in_sizes, int n_in,
                              void* d_out, int out_size, void* d_ws, size_t ws_size,
                              hipStream_t stream) {
  const float* x  = (const float*)d_in[0];
  const float* Wq = (const float*)d_in[1];
  const float* Wk = (const float*)d_in[2];
  const float* Wv = (const float*)d_in[3];
  const float* Wo = (const float*)d_in[4];
  const float* bo = (const float*)d_in[5];
  float* out = (float*)d_out;

  char* ws = (char*)d_ws;
  unsigned short* xb    = (unsigned short*)(ws);              // 4096x768 bf16
  unsigned short* wqb   = (unsigned short*)(ws + 6291456);
  unsigned short* wkb   = (unsigned short*)(ws + 7471104);
  unsigned short* wvb   = (unsigned short*)(ws + 8650752);
  unsigned short* wob   = (unsigned short*)(ws + 9830400);
  unsigned short* q_ws  = (unsigned short*)(ws + 11010048);   // [b,h,s,64]
  unsigned short* k_ws  = (unsigned short*)(ws + 17301504);   // [b,h,s,64]
  unsigned short* vt_ws = (unsigned short*)(ws + 23592960);   // [b,h,64,s]
  unsigned short* ctx   = (unsigned short*)(ws + 29884416);   // [b,s,768]
  // total 36,175,872 B

  cvt_kernel<<<3072, 256, 0, stream>>>(x,  xb,  786432);
  cvt_kernel<<<576,  256, 0, stream>>>(Wq, wqb, 147456);
  cvt_kernel<<<576,  256, 0, stream>>>(Wk, wkb, 147456);
  cvt_kernel<<<576,  256, 0, stream>>>(Wv, wvb, 147456);
  cvt_kernel<<<576,  256, 0, stream>>>(Wo, wob, 147456);
  qkv_gemm<<<dim3(32, 18), 256, 0, stream>>>(xb, wqb, wkb, wvb, q_ws, k_ws, vt_ws);
  attn_kernel<<<dim3(16, 24), 256, 0, stream>>>(q_ws, k_ws, vt_ws, ctx);
  out_gemm<<<dim3(32, 6), 256, 0, stream>>>(ctx, wob, bo, out);
}

// Round 2
// 147.409 us; speedup vs baseline: 1.3959x; 1.3959x over previous
//
#include <hip/hip_runtime.h>
#include <stdint.h>

typedef __attribute__((ext_vector_type(4))) float f32x4;
typedef __attribute__((ext_vector_type(8))) short s16x8;

#if __has_builtin(__builtin_amdgcn_exp2f)
#define EXP2(x) __builtin_amdgcn_exp2f(x)
#else
#define EXP2(x) exp2f(x)
#endif

__device__ __forceinline__ unsigned short tobf(float x) {
  uint32_t u = __builtin_bit_cast(uint32_t, x);
  u += 0x7fffu + ((u >> 16) & 1u);   // RNE
  return (unsigned short)(u >> 16);
}

// ---------------- fp32 -> bf16 convert ----------------
__global__ __launch_bounds__(256) void cvt_kernel(const float* __restrict__ in,
                                                  unsigned short* __restrict__ out, int n4) {
  int i = blockIdx.x * 256 + threadIdx.x;
  if (i >= n4) return;
  float4 v = reinterpret_cast<const float4*>(in)[i];
  ushort4 o;
  o.x = tobf(v.x); o.y = tobf(v.y); o.z = tobf(v.z); o.w = tobf(v.w);
  reinterpret_cast<ushort4*>(out)[i] = o;
}

// ---------------- fused QKV projection: C = xb @ W^T ----------------
// grid (32, 18): y in [0,6)->Q, [6,12)->K, [12,18)->V ; 128x128 tile, 4 waves.
__global__ __launch_bounds__(256) void qkv_gemm(
    const unsigned short* __restrict__ xb,
    const unsigned short* __restrict__ wq,
    const unsigned short* __restrict__ wk,
    const unsigned short* __restrict__ wv,
    unsigned short* __restrict__ q_ws,
    unsigned short* __restrict__ k_ws,
    unsigned short* __restrict__ vt_ws) {
  __shared__ unsigned short As[128][40];
  __shared__ unsigned short Bs[128][40];
  const int t = threadIdx.x;
  const int l = t & 63, w = t >> 6;
  const int wm = w >> 1, wn = w & 1;
  const int lr = l & 15, lg = l >> 4;
  const int tileM = blockIdx.x * 128;
  const int nt = blockIdx.y;
  const int wsel = nt / 6;
  const unsigned short* W = (wsel == 0) ? wq : ((wsel == 1) ? wk : wv);
  const int tileN = (nt % 6) * 128;

  f32x4 acc[4][4];
  const f32x4 z4 = {0.f, 0.f, 0.f, 0.f};
#pragma unroll
  for (int i = 0; i < 4; ++i)
#pragma unroll
    for (int j = 0; j < 4; ++j) acc[i][j] = z4;

  for (int k0 = 0; k0 < 768; k0 += 32) {
    __syncthreads();
#pragma unroll
    for (int i = 0; i < 2; ++i) {
      int L = i * 256 + t;
      int row = L >> 2, cb = (L & 3) * 8;
      *(uint4*)&As[row][cb] = *(const uint4*)&xb[(tileM + row) * 768 + k0 + cb];
      *(uint4*)&Bs[row][cb] = *(const uint4*)&W[(tileN + row) * 768 + k0 + cb];
    }
    __syncthreads();
    s16x8 a[4], b[4];
#pragma unroll
    for (int mi = 0; mi < 4; ++mi) a[mi] = *(const s16x8*)&As[wm * 64 + mi * 16 + lr][lg * 8];
#pragma unroll
    for (int ni = 0; ni < 4; ++ni) b[ni] = *(const s16x8*)&Bs[wn * 64 + ni * 16 + lr][lg * 8];
#pragma unroll
    for (int mi = 0; mi < 4; ++mi)
#pragma unroll
      for (int ni = 0; ni < 4; ++ni)
        acc[mi][ni] = __builtin_amdgcn_mfma_f32_16x16x32_bf16(a[mi], b[ni], acc[mi][ni], 0, 0, 0);
  }

#pragma unroll
  for (int mi = 0; mi < 4; ++mi)
#pragma unroll
    for (int ni = 0; ni < 4; ++ni)
#pragma unroll
      for (int r = 0; r < 4; ++r) {
        int m = tileM + wm * 64 + mi * 16 + lg * 4 + r;
        int n = tileN + wn * 64 + ni * 16 + lr;
        int bb = m >> 11, sq = m & 2047;
        int h = n >> 6, dh = n & 63;
        float v = acc[mi][ni][r];
        if (wsel == 0)       // Q, pre-scaled by (1/sqrt(Dh)) * log2(e)  -> exp2 domain
          q_ws[((bb * 12 + h) * 2048 + sq) * 64 + dh] = tobf(v * 0.18033688011112042f);
        else if (wsel == 1)  // K
          k_ws[((bb * 12 + h) * 2048 + sq) * 64 + dh] = tobf(v);
        else                 // V stored transposed: [b,h,64,s]
          vt_ws[((bb * 12 + h) * 64 + dh) * 2048 + sq] = tobf(v);
      }
}

// ---------------- flash attention (causal), swapped-operand layout ----------------
// grid (32, 24): x -> q-tile (reversed, QBLK=64), y -> b*12+h.
// Block: 4 waves x 16 q-rows; k-tiles of 64.
// S^T = mfma(K, Q): lane holds q = lane&15, k = ni*16 + (lane>>4)*4 + r  -> row-reduce
// is register-local + 2 shuffles. O^T = mfma(V^T, P): accumulator also has q = lane&15,
// so online-softmax rescale and final 1/l are lane-local (zero shuffles).
__global__ __launch_bounds__(256) void attn_kernel(
    const unsigned short* __restrict__ q_ws,
    const unsigned short* __restrict__ k_ws,
    const unsigned short* __restrict__ vt_ws,
    unsigned short* __restrict__ ctx) {
  __shared__ unsigned short Ks[64][72];      // [k][d]
  __shared__ unsigned short Vs[64][72];      // V^T tile: [d][k]
  __shared__ unsigned short Ps[4][16][72];   // wave-private P: [q][k]

  const int t = threadIdx.x;
  const int l = t & 63, w = t >> 6;
  const int lr = l & 15, lg = l >> 4;
  const int qt = 31 - (int)blockIdx.x;       // heavy tiles dispatch first
  const int bh = blockIdx.y;
  const int q_base = qt * 64 + w * 16;
  const int qg = q_base + lr;                // this lane's q-row

  s16x8 qa[2];  // Q as B-operand: [k=d][n=q];  lane: q=lr, d=kk*32+lg*8+j
#pragma unroll
  for (int kk = 0; kk < 2; ++kk)
    qa[kk] = *(const s16x8*)&q_ws[(bh * 2048 + qg) * 64 + kk * 32 + lg * 8];

  f32x4 o[4];                                // O^T: lane q=lr, d = di*16 + lg*4 + r
  const f32x4 z4 = {0.f, 0.f, 0.f, 0.f};
#pragma unroll
  for (int di = 0; di < 4; ++di) o[di] = z4;
  float mrun = -1e30f, lrun = 0.f;

  for (int kt = 0; kt <= qt; ++kt) {
    const int k0 = kt * 64;
    __syncthreads();
#pragma unroll
    for (int i = 0; i < 2; ++i) {
      int L = i * 256 + t;
      int row = L >> 3, cb = (L & 7) * 8;
      *(uint4*)&Ks[row][cb] = *(const uint4*)&k_ws[(bh * 2048 + k0 + row) * 64 + cb];
      *(uint4*)&Vs[row][cb] = *(const uint4*)&vt_ws[(bh * 64 + row) * 2048 + k0 + cb];
    }
    __syncthreads();

    // S^T = K . Q^T : s[ni][r] = S[q=lr][k0 + ni*16 + lg*4 + r]
    f32x4 s[4];
#pragma unroll
    for (int ni = 0; ni < 4; ++ni) s[ni] = z4;
#pragma unroll
    for (int kk = 0; kk < 2; ++kk) {
      s16x8 kb[4];
#pragma unroll
      for (int ni = 0; ni < 4; ++ni) kb[ni] = *(const s16x8*)&Ks[ni * 16 + lr][kk * 32 + lg * 8];
#pragma unroll
      for (int ni = 0; ni < 4; ++ni)
        s[ni] = __builtin_amdgcn_mfma_f32_16x16x32_bf16(kb[ni], qa[kk], s[ni], 0, 0, 0);
    }

    if (kt == qt) {  // diagonal tile: causal mask
#pragma unroll
      for (int ni = 0; ni < 4; ++ni)
#pragma unroll
        for (int r = 0; r < 4; ++r) {
          int kg = k0 + ni * 16 + lg * 4 + r;
          if (kg > qg) s[ni][r] = -1e30f;
        }
    }

    // online softmax (log2 domain), per-lane row stats
    float mx = s[0][0];
#pragma unroll
    for (int ni = 0; ni < 4; ++ni)
#pragma unroll
      for (int r = 0; r < 4; ++r) mx = fmaxf(mx, s[ni][r]);
    mx = fmaxf(mx, __shfl_xor(mx, 16));
    mx = fmaxf(mx, __shfl_xor(mx, 32));
    float mnew = fmaxf(mrun, mx);
    float alpha = EXP2(mrun - mnew);
    mrun = mnew;
    float rs = 0.f;
#pragma unroll
    for (int ni = 0; ni < 4; ++ni)
#pragma unroll
      for (int r = 0; r < 4; ++r) {
        float p = EXP2(s[ni][r] - mnew);
        s[ni][r] = p;
        rs += p;
      }
    rs += __shfl_xor(rs, 16);
    rs += __shfl_xor(rs, 32);
    lrun = lrun * alpha + rs;
#pragma unroll
    for (int di = 0; di < 4; ++di)
#pragma unroll
      for (int r = 0; r < 4; ++r) o[di][r] *= alpha;

    // P -> bf16 -> wave-private LDS [q][k] (packed pairs)
#pragma unroll
    for (int ni = 0; ni < 4; ++ni)
#pragma unroll
      for (int hh = 0; hh < 2; ++hh) {
        uint32_t pw = (uint32_t)tobf(s[ni][2 * hh]) | ((uint32_t)tobf(s[ni][2 * hh + 1]) << 16);
        *(uint32_t*)&Ps[w][lr][ni * 16 + lg * 4 + 2 * hh] = pw;
      }

    // O^T += V^T . P^T : o[di] = mfma(A=V^T, B=P)
#pragma unroll
    for (int kk = 0; kk < 2; ++kk) {
      s16x8 pa = *(const s16x8*)&Ps[w][lr][kk * 32 + lg * 8];
#pragma unroll
      for (int di = 0; di < 4; ++di) {
        s16x8 vb = *(const s16x8*)&Vs[di * 16 + lr][kk * 32 + lg * 8];
        o[di] = __builtin_amdgcn_mfma_f32_16x16x32_bf16(vb, pa, o[di], 0, 0, 0);
      }
    }
  }

  const int bb = bh / 12, hh = bh % 12;
  const float rl = 1.0f / lrun;
#pragma unroll
  for (int di = 0; di < 4; ++di)
#pragma unroll
    for (int r = 0; r < 4; ++r) {
      int d = di * 16 + lg * 4 + r;
      ctx[(bb * 2048 + qg) * 768 + hh * 64 + d] = tobf(o[di][r] * rl);
    }
}

// ---------------- output projection: out = ctx @ Wo^T + bo (fp32 out) ----------------
__global__ __launch_bounds__(256) void out_gemm(
    const unsigned short* __restrict__ ctxb,
    const unsigned short* __restrict__ wo,
    const float* __restrict__ bo,
    float* __restrict__ out) {
  __shared__ unsigned short As[128][40];
  __shared__ unsigned short Bs[128][40];
  const int t = threadIdx.x;
  const int l = t & 63, w = t >> 6;
  const int wm = w >> 1, wn = w & 1;
  const int lr = l & 15, lg = l >> 4;
  const int tileM = blockIdx.x * 128;
  const int tileN = blockIdx.y * 128;

  f32x4 acc[4][4];
  const f32x4 z4 = {0.f, 0.f, 0.f, 0.f};
#pragma unroll
  for (int i = 0; i < 4; ++i)
#pragma unroll
    for (int j = 0; j < 4; ++j) acc[i][j] = z4;

  for (int k0 = 0; k0 < 768; k0 += 32) {
    __syncthreads();
#pragma unroll
    for (int i = 0; i < 2; ++i) {
      int L = i * 256 + t;
      int row = L >> 2, cb = (L & 3) * 8;
      *(uint4*)&As[row][cb] = *(const uint4*)&ctxb[(tileM + row) * 768 + k0 + cb];
      *(uint4*)&Bs[row][cb] = *(const uint4*)&wo[(tileN + row) * 768 + k0 + cb];
    }
    __syncthreads();
    s16x8 a[4], b[4];
#pragma unroll
    for (int mi = 0; mi < 4; ++mi) a[mi] = *(const s16x8*)&As[wm * 64 + mi * 16 + lr][lg * 8];
#pragma unroll
    for (int ni = 0; ni < 4; ++ni) b[ni] = *(const s16x8*)&Bs[wn * 64 + ni * 16 + lr][lg * 8];
#pragma unroll
    for (int mi = 0; mi < 4; ++mi)
#pragma unroll
      for (int ni = 0; ni < 4; ++ni)
        acc[mi][ni] = __builtin_amdgcn_mfma_f32_16x16x32_bf16(a[mi], b[ni], acc[mi][ni], 0, 0, 0);
  }

#pragma unroll
  for (int mi = 0; mi < 4; ++mi)
#pragma unroll
    for (int ni = 0; ni < 4; ++ni)
#pragma unroll
      for (int r = 0; r < 4; ++r) {
        int m = tileM + wm * 64 + mi * 16 + lg * 4 + r;
        int n = tileN + wn * 64 + ni * 16 + lr;
        out[m * 768 + n] = acc[mi][ni][r] + bo[n];
      }
}

// ---------------- launch ----------------
extern "C" void kernel_launch(void* const* d_in, const int* in_sizes, int n_in,
                              void* d_out, int out_size, void* d_ws, size_t ws_size,
                              hipStream_t stream) {
  const float* x  = (const float*)d_in[0];
  const float* Wq = (const float*)d_in[1];
  const float* Wk = (const float*)d_in[2];
  const float* Wv = (const float*)d_in[3];
  const float* Wo = (const float*)d_in[4];
  const float* bo = (const float*)d_in[5];
  float* out = (float*)d_out;

  char* ws = (char*)d_ws;
  unsigned short* xb    = (unsigned short*)(ws);              // 4096x768 bf16
  unsigned short* wqb   = (unsigned short*)(ws + 6291456);
  unsigned short* wkb   = (unsigned short*)(ws + 7471104);
  unsigned short* wvb   = (unsigned short*)(ws + 8650752);
  unsigned short* wob   = (unsigned short*)(ws + 9830400);
  unsigned short* q_ws  = (unsigned short*)(ws + 11010048);   // [b,h,s,64]
  unsigned short* k_ws  = (unsigned short*)(ws + 17301504);   // [b,h,s,64]
  unsigned short* vt_ws = (unsigned short*)(ws + 23592960);   // [b,h,64,s]
  unsigned short* ctx   = (unsigned short*)(ws + 29884416);   // [b,s,768]

  cvt_kernel<<<3072, 256, 0, stream>>>(x,  xb,  786432);
  cvt_kernel<<<576,  256, 0, stream>>>(Wq, wqb, 147456);
  cvt_kernel<<<576,  256, 0, stream>>>(Wk, wkb, 147456);
  cvt_kernel<<<576,  256, 0, stream>>>(Wv, wvb, 147456);
  cvt_kernel<<<576,  256, 0, stream>>>(Wo, wob, 147456);
  qkv_gemm<<<dim3(32, 18), 256, 0, stream>>>(xb, wqb, wkb, wvb, q_ws, k_ws, vt_ws);
  attn_kernel<<<dim3(32, 24), 256, 0, stream>>>(q_ws, k_ws, vt_ws, ctx);
  out_gemm<<<dim3(32, 6), 256, 0, stream>>>(ctx, wob, bo, out);
}

// Round 3
// 125.970 us; speedup vs baseline: 1.6335x; 1.1702x over previous
//
#include <hip/hip_runtime.h>
#include <stdint.h>

typedef __attribute__((ext_vector_type(4))) float f32x4;
typedef __attribute__((ext_vector_type(8))) short s16x8;

#if __has_builtin(__builtin_amdgcn_exp2f)
#define EXP2(x) __builtin_amdgcn_exp2f(x)
#else
#define EXP2(x) exp2f(x)
#endif

// async global->LDS, 16B per lane (dest = wave-uniform base + lane*16, linear)
#define GL2LDS(g, s)                                                        \
  __builtin_amdgcn_global_load_lds(                                         \
      (const __attribute__((address_space(1))) void*)(g),                   \
      (__attribute__((address_space(3))) void*)(s), 16, 0, 0)

__device__ __forceinline__ unsigned short tobf(float x) {
  uint32_t u = __builtin_bit_cast(uint32_t, x);
  u += 0x7fffu + ((u >> 16) & 1u);   // RNE
  return (unsigned short)(u >> 16);
}

// ---------------- fp32 -> bf16 convert ----------------
__global__ __launch_bounds__(256) void cvt_kernel(const float* __restrict__ in,
                                                  unsigned short* __restrict__ out, int n4) {
  int i = blockIdx.x * 256 + threadIdx.x;
  if (i >= n4) return;
  float4 v = reinterpret_cast<const float4*>(in)[i];
  ushort4 o;
  o.x = tobf(v.x); o.y = tobf(v.y); o.z = tobf(v.z); o.w = tobf(v.w);
  reinterpret_cast<ushort4*>(out)[i] = o;
}

// ---------------- fused QKV projection: C = xb @ W^T (m97 structure) ----------------
// grid (32, 18): y in [0,6)->Q, [6,12)->K, [12,18)->V ; 128x128 tile, BK=32, 4 waves.
// Staging via global_load_lds width=16 into linear LDS (no pad).
__global__ __launch_bounds__(256) void qkv_gemm(
    const unsigned short* __restrict__ xb,
    const unsigned short* __restrict__ wq,
    const unsigned short* __restrict__ wk,
    const unsigned short* __restrict__ wv,
    unsigned short* __restrict__ q_ws,
    unsigned short* __restrict__ k_ws,
    unsigned short* __restrict__ vt_ws) {
  __shared__ unsigned short As[128][32];
  __shared__ unsigned short Bs[128][32];
  const int t = threadIdx.x;
  const int l = t & 63, w = t >> 6;
  const int wm = w >> 1, wn = w & 1;
  const int lr = l & 15, lg = l >> 4;
  const int tileM = blockIdx.x * 128;
  const int nt = blockIdx.y;
  const int wsel = nt / 6;
  const unsigned short* W = (wsel == 0) ? wq : ((wsel == 1) ? wk : wv);
  const int tileN = (nt % 6) * 128;

  // staging geometry: call i covers 16 rows (w*32 + i*16), lane -> row l>>2, chunk l&3
  const int srow = l >> 2;
  const int scol = (l & 3) * 8;

  f32x4 acc[4][4];
  const f32x4 z4 = {0.f, 0.f, 0.f, 0.f};
#pragma unroll
  for (int i = 0; i < 4; ++i)
#pragma unroll
    for (int j = 0; j < 4; ++j) acc[i][j] = z4;

  for (int k0 = 0; k0 < 768; k0 += 32) {
    __syncthreads();
#pragma unroll
    for (int i = 0; i < 2; ++i) {
      int r0 = w * 32 + i * 16;
      GL2LDS(&xb[(tileM + r0 + srow) * 768 + k0 + scol], &As[r0][0]);
      GL2LDS(&W [(tileN + r0 + srow) * 768 + k0 + scol], &Bs[r0][0]);
    }
    __syncthreads();
    s16x8 a[4], b[4];
#pragma unroll
    for (int mi = 0; mi < 4; ++mi) a[mi] = *(const s16x8*)&As[wm * 64 + mi * 16 + lr][lg * 8];
#pragma unroll
    for (int ni = 0; ni < 4; ++ni) b[ni] = *(const s16x8*)&Bs[wn * 64 + ni * 16 + lr][lg * 8];
#pragma unroll
    for (int mi = 0; mi < 4; ++mi)
#pragma unroll
      for (int ni = 0; ni < 4; ++ni)
        acc[mi][ni] = __builtin_amdgcn_mfma_f32_16x16x32_bf16(a[mi], b[ni], acc[mi][ni], 0, 0, 0);
  }

#pragma unroll
  for (int mi = 0; mi < 4; ++mi)
#pragma unroll
    for (int ni = 0; ni < 4; ++ni)
#pragma unroll
      for (int r = 0; r < 4; ++r) {
        int m = tileM + wm * 64 + mi * 16 + lg * 4 + r;
        int n = tileN + wn * 64 + ni * 16 + lr;
        int bb = m >> 11, sq = m & 2047;
        int h = n >> 6, dh = n & 63;
        float v = acc[mi][ni][r];
        if (wsel == 0)       // Q, pre-scaled by (1/sqrt(Dh)) * log2(e)  -> exp2 domain
          q_ws[((bb * 12 + h) * 2048 + sq) * 64 + dh] = tobf(v * 0.18033688011112042f);
        else if (wsel == 1)  // K
          k_ws[((bb * 12 + h) * 2048 + sq) * 64 + dh] = tobf(v);
        else                 // V stored transposed: [b,h,64,s]
          vt_ws[((bb * 12 + h) * 64 + dh) * 2048 + sq] = tobf(v);
      }
}

// ---------------- flash attention (causal), swapped-operand + dbuf prefetch ----------------
// grid (32, 24): x -> q-tile (reversed, QBLK=64), y -> b*12+h. 4 waves x 16 q-rows.
// S^T = mfma(K, Q); O^T = mfma(V^T, P): q = lane&15 everywhere -> lane-local softmax stats.
// K/V double-buffered; next tile's global loads issued at top of compute (T14),
// ds_write after barrier; defer-max rescale (T13, THR=8 in log2 domain).
__global__ __launch_bounds__(256) void attn_kernel(
    const unsigned short* __restrict__ q_ws,
    const unsigned short* __restrict__ k_ws,
    const unsigned short* __restrict__ vt_ws,
    unsigned short* __restrict__ ctx) {
  __shared__ unsigned short Ks[2][64][72];
  __shared__ unsigned short Vs[2][64][72];
  __shared__ unsigned short Ps[4][16][72];

  const int t = threadIdx.x;
  const int l = t & 63, w = t >> 6;
  const int lr = l & 15, lg = l >> 4;
  const int qt = 31 - (int)blockIdx.x;       // heavy tiles dispatch first
  const int bh = blockIdx.y;
  const int q_base = qt * 64 + w * 16;
  const int qg = q_base + lr;                // this lane's q-row

  // staging share: thread handles row t>>2 (of 64), 32B span at chunk (t&3)*16
  const int srow = t >> 2;
  const int scol = (t & 3) * 16;
  const unsigned short* kbase = &k_ws[(bh * 2048 + srow) * 64 + scol];
  const unsigned short* vbase = &vt_ws[(bh * 64 + srow) * 2048 + scol];

  s16x8 qa[2];  // Q as B-operand; lane: q=lr, d=kk*32+lg*8+j  (already exp2-scaled)
#pragma unroll
  for (int kk = 0; kk < 2; ++kk)
    qa[kk] = *(const s16x8*)&q_ws[(bh * 2048 + qg) * 64 + kk * 32 + lg * 8];

  f32x4 o[4];                                // O^T: lane q=lr, d = di*16 + lg*4 + r
  const f32x4 z4 = {0.f, 0.f, 0.f, 0.f};
#pragma unroll
  for (int di = 0; di < 4; ++di) o[di] = z4;
  float mrun = -1e30f, lrun = 0.f;

  uint4 kr0, kr1, vr0, vr1;
  // prologue: load tile 0 -> regs -> LDS buf0
  kr0 = *(const uint4*)(kbase);      kr1 = *(const uint4*)(kbase + 8);
  vr0 = *(const uint4*)(vbase);      vr1 = *(const uint4*)(vbase + 8);
  {
    unsigned short* kd = &Ks[0][srow][scol];
    *(uint4*)kd = kr0; *(uint4*)(kd + 8) = kr1;
    unsigned short* vd = &Vs[0][srow][scol];
    *(uint4*)vd = vr0; *(uint4*)(vd + 8) = vr1;
  }
  __syncthreads();
  int c = 0;

  for (int kt = 0; kt <= qt; ++kt) {
    const int k0 = kt * 64;
    const bool pf = (kt < qt);
    if (pf) {  // issue next tile's loads now; latency hides under compute
      kr0 = *(const uint4*)(kbase + (k0 + 64) * 64);
      kr1 = *(const uint4*)(kbase + (k0 + 64) * 64 + 8);
      vr0 = *(const uint4*)(vbase + (k0 + 64));
      vr1 = *(const uint4*)(vbase + (k0 + 64) + 8);
    }

    // S^T = K . Q^T : s[ni][r] = S[q=lr][k0 + ni*16 + lg*4 + r]
    f32x4 s[4];
#pragma unroll
    for (int ni = 0; ni < 4; ++ni) s[ni] = z4;
#pragma unroll
    for (int kk = 0; kk < 2; ++kk) {
      s16x8 kb[4];
#pragma unroll
      for (int ni = 0; ni < 4; ++ni) kb[ni] = *(const s16x8*)&Ks[c][ni * 16 + lr][kk * 32 + lg * 8];
#pragma unroll
      for (int ni = 0; ni < 4; ++ni)
        s[ni] = __builtin_amdgcn_mfma_f32_16x16x32_bf16(kb[ni], qa[kk], s[ni], 0, 0, 0);
    }

    if (kt == qt) {  // diagonal tile: causal mask
#pragma unroll
      for (int ni = 0; ni < 4; ++ni)
#pragma unroll
        for (int r = 0; r < 4; ++r) {
          int kg = k0 + ni * 16 + lg * 4 + r;
          if (kg > qg) s[ni][r] = -1e30f;
        }
    }

    // online softmax (exp2 domain), lane-local stats + 2 shuffles
    float mx = s[0][0];
#pragma unroll
    for (int ni = 0; ni < 4; ++ni)
#pragma unroll
      for (int r = 0; r < 4; ++r) mx = fmaxf(mx, s[ni][r]);
    mx = fmaxf(mx, __shfl_xor(mx, 16));
    mx = fmaxf(mx, __shfl_xor(mx, 32));
    if (!__all(mx - mrun <= 8.0f)) {  // defer-max: skip rescale when growth small
      float mnew = fmaxf(mrun, mx);
      float alpha = EXP2(mrun - mnew);
      lrun *= alpha;
#pragma unroll
      for (int di = 0; di < 4; ++di)
#pragma unroll
        for (int r = 0; r < 4; ++r) o[di][r] *= alpha;
      mrun = mnew;
    }
    float rs = 0.f;
#pragma unroll
    for (int ni = 0; ni < 4; ++ni)
#pragma unroll
      for (int r = 0; r < 4; ++r) {
        float p = EXP2(s[ni][r] - mrun);
        s[ni][r] = p;
        rs += p;
      }
    rs += __shfl_xor(rs, 16);
    rs += __shfl_xor(rs, 32);
    lrun += rs;

    // P -> bf16 -> wave-private LDS [q][k] (packed pairs; intra-wave, no barrier)
#pragma unroll
    for (int ni = 0; ni < 4; ++ni)
#pragma unroll
      for (int hh = 0; hh < 2; ++hh) {
        uint32_t pw = (uint32_t)tobf(s[ni][2 * hh]) | ((uint32_t)tobf(s[ni][2 * hh + 1]) << 16);
        *(uint32_t*)&Ps[w][lr][ni * 16 + lg * 4 + 2 * hh] = pw;
      }

    // O^T += V^T . P^T
#pragma unroll
    for (int kk = 0; kk < 2; ++kk) {
      s16x8 pa = *(const s16x8*)&Ps[w][lr][kk * 32 + lg * 8];
#pragma unroll
      for (int di = 0; di < 4; ++di) {
        s16x8 vb = *(const s16x8*)&Vs[c][di * 16 + lr][kk * 32 + lg * 8];
        o[di] = __builtin_amdgcn_mfma_f32_16x16x32_bf16(vb, pa, o[di], 0, 0, 0);
      }
    }

    if (pf) {
      __syncthreads();  // all waves done reading buf c^1 (last read in iter kt-1)
      unsigned short* kd = &Ks[c ^ 1][srow][scol];
      *(uint4*)kd = kr0; *(uint4*)(kd + 8) = kr1;   // waits vmcnt via data dep
      unsigned short* vd = &Vs[c ^ 1][srow][scol];
      *(uint4*)vd = vr0; *(uint4*)(vd + 8) = vr1;
      __syncthreads();  // buf c^1 ready
      c ^= 1;
    }
  }

  const int bb = bh / 12, hh = bh % 12;
  const float rl = 1.0f / lrun;
#pragma unroll
  for (int di = 0; di < 4; ++di)
#pragma unroll
    for (int r = 0; r < 4; ++r) {
      int d = di * 16 + lg * 4 + r;
      ctx[(bb * 2048 + qg) * 768 + hh * 64 + d] = tobf(o[di][r] * rl);
    }
}

// ---------------- output projection: out = ctx @ Wo^T + bo (m97 structure, fp32 out) ----------------
__global__ __launch_bounds__(256) void out_gemm(
    const unsigned short* __restrict__ ctxb,
    const unsigned short* __restrict__ wo,
    const float* __restrict__ bo,
    float* __restrict__ out) {
  __shared__ unsigned short As[128][32];
  __shared__ unsigned short Bs[128][32];
  const int t = threadIdx.x;
  const int l = t & 63, w = t >> 6;
  const int wm = w >> 1, wn = w & 1;
  const int lr = l & 15, lg = l >> 4;
  const int tileM = blockIdx.x * 128;
  const int tileN = blockIdx.y * 128;
  const int srow = l >> 2;
  const int scol = (l & 3) * 8;

  f32x4 acc[4][4];
  const f32x4 z4 = {0.f, 0.f, 0.f, 0.f};
#pragma unroll
  for (int i = 0; i < 4; ++i)
#pragma unroll
    for (int j = 0; j < 4; ++j) acc[i][j] = z4;

  for (int k0 = 0; k0 < 768; k0 += 32) {
    __syncthreads();
#pragma unroll
    for (int i = 0; i < 2; ++i) {
      int r0 = w * 32 + i * 16;
      GL2LDS(&ctxb[(tileM + r0 + srow) * 768 + k0 + scol], &As[r0][0]);
      GL2LDS(&wo  [(tileN + r0 + srow) * 768 + k0 + scol], &Bs[r0][0]);
    }
    __syncthreads();
    s16x8 a[4], b[4];
#pragma unroll
    for (int mi = 0; mi < 4; ++mi) a[mi] = *(const s16x8*)&As[wm * 64 + mi * 16 + lr][lg * 8];
#pragma unroll
    for (int ni = 0; ni < 4; ++ni) b[ni] = *(const s16x8*)&Bs[wn * 64 + ni * 16 + lr][lg * 8];
#pragma unroll
    for (int mi = 0; mi < 4; ++mi)
#pragma unroll
      for (int ni = 0; ni < 4; ++ni)
        acc[mi][ni] = __builtin_amdgcn_mfma_f32_16x16x32_bf16(a[mi], b[ni], acc[mi][ni], 0, 0, 0);
  }

#pragma unroll
  for (int mi = 0; mi < 4; ++mi)
#pragma unroll
    for (int ni = 0; ni < 4; ++ni)
#pragma unroll
      for (int r = 0; r < 4; ++r) {
        int m = tileM + wm * 64 + mi * 16 + lg * 4 + r;
        int n = tileN + wn * 64 + ni * 16 + lr;
        out[m * 768 + n] = acc[mi][ni][r] + bo[n];
      }
}

// ---------------- launch ----------------
extern "C" void kernel_launch(void* const* d_in, const int* in_sizes, int n_in,
                              void* d_out, int out_size, void* d_ws, size_t ws_size,
                              hipStream_t stream) {
  const float* x  = (const float*)d_in[0];
  const float* Wq = (const float*)d_in[1];
  const float* Wk = (const float*)d_in[2];
  const float* Wv = (const float*)d_in[3];
  const float* Wo = (const float*)d_in[4];
  const float* bo = (const float*)d_in[5];
  float* out = (float*)d_out;

  char* ws = (char*)d_ws;
  unsigned short* xb    = (unsigned short*)(ws);              // 4096x768 bf16
  unsigned short* wqb   = (unsigned short*)(ws + 6291456);
  unsigned short* wkb   = (unsigned short*)(ws + 7471104);
  unsigned short* wvb   = (unsigned short*)(ws + 8650752);
  unsigned short* wob   = (unsigned short*)(ws + 9830400);
  unsigned short* q_ws  = (unsigned short*)(ws + 11010048);   // [b,h,s,64]
  unsigned short* k_ws  = (unsigned short*)(ws + 17301504);   // [b,h,s,64]
  unsigned short* vt_ws = (unsigned short*)(ws + 23592960);   // [b,h,64,s]
  unsigned short* ctx   = (unsigned short*)(ws + 29884416);   // [b,s,768]

  cvt_kernel<<<3072, 256, 0, stream>>>(x,  xb,  786432);
  cvt_kernel<<<576,  256, 0, stream>>>(Wq, wqb, 147456);
  cvt_kernel<<<576,  256, 0, stream>>>(Wk, wkb, 147456);
  cvt_kernel<<<576,  256, 0, stream>>>(Wv, wvb, 147456);
  cvt_kernel<<<576,  256, 0, stream>>>(Wo, wob, 147456);
  qkv_gemm<<<dim3(32, 18), 256, 0, stream>>>(xb, wqb, wkb, wvb, q_ws, k_ws, vt_ws);
  attn_kernel<<<dim3(32, 24), 256, 0, stream>>>(q_ws, k_ws, vt_ws, ctx);
  out_gemm<<<dim3(32, 6), 256, 0, stream>>>(ctx, wob, bo, out);
}